// Round 1
// baseline (13525.584 us; speedup 1.0000x reference)
//
#include <hip/hip_runtime.h>
#include <hip/hip_bf16.h>

#define B_   8
#define C_   512
#define C8_  64
#define N_   4096   // 64*64 spatial

// ---------------------------------------------------------------------------
// proj: out[b][o][n] = sum_c W[o][c] * x[b][c][n] + bias[o]
// 64(o) x 64(n) tile per block, K-step 32. Thread computes 4x4 micro-tile.
// ---------------------------------------------------------------------------
__global__ __launch_bounds__(256) void proj_kernel(
    const float* __restrict__ x, const float* __restrict__ W,
    const float* __restrict__ bias, float* __restrict__ out, int O) {
  const int b  = blockIdx.z;
  const int n0 = blockIdx.x * 64;
  const int o0 = blockIdx.y * 64;
  __shared__ float xs[32][64];    // [c][n]
  __shared__ float wsT[32][68];   // [c][o], padded (16B-aligned rows)
  const int t  = threadIdx.x;
  const int tn = t & 15;          // n-group (4 floats each)
  const int to = t >> 4;          // o-group (4 floats each)

  float acc[4][4];
#pragma unroll
  for (int i = 0; i < 4; ++i)
#pragma unroll
    for (int j = 0; j < 4; ++j) acc[i][j] = 0.f;

  const float* xb = x + (size_t)b * C_ * N_ + n0;
  for (int c0 = 0; c0 < C_; c0 += 32) {
    // stage X tile: 32c x 64n, coalesced
#pragma unroll
    for (int i = 0; i < 8; ++i) {
      int idx = t + i * 256;          // 0..2047
      int cc = idx >> 6, nn = idx & 63;
      xs[cc][nn] = xb[(size_t)(c0 + cc) * N_ + nn];
    }
    // stage W tile transposed: read [o][c] coalesced over c, write [c][o]
#pragma unroll
    for (int i = 0; i < 8; ++i) {
      int idx = t + i * 256;
      int cc = idx & 31, oo = idx >> 5;
      wsT[cc][oo] = W[(size_t)(o0 + oo) * C_ + c0 + cc];
    }
    __syncthreads();
#pragma unroll
    for (int cc = 0; cc < 32; ++cc) {
      float4 xv = ((const float4*)&xs[cc][0])[tn];
      float4 wv = ((const float4*)&wsT[cc][0])[to];
      acc[0][0] += wv.x * xv.x; acc[0][1] += wv.x * xv.y;
      acc[0][2] += wv.x * xv.z; acc[0][3] += wv.x * xv.w;
      acc[1][0] += wv.y * xv.x; acc[1][1] += wv.y * xv.y;
      acc[1][2] += wv.y * xv.z; acc[1][3] += wv.y * xv.w;
      acc[2][0] += wv.z * xv.x; acc[2][1] += wv.z * xv.y;
      acc[2][2] += wv.z * xv.z; acc[2][3] += wv.z * xv.w;
      acc[3][0] += wv.w * xv.x; acc[3][1] += wv.w * xv.y;
      acc[3][2] += wv.w * xv.z; acc[3][3] += wv.w * xv.w;
    }
    __syncthreads();
  }
#pragma unroll
  for (int i = 0; i < 4; ++i) {
    int oo = to * 4 + i;
    float bv = bias[o0 + oo];
    float4 r;
    r.x = acc[i][0] + bv; r.y = acc[i][1] + bv;
    r.z = acc[i][2] + bv; r.w = acc[i][3] + bv;
    *(float4*)&out[((size_t)b * O + o0 + oo) * N_ + n0 + tn * 4] = r;
  }
}

// ---------------------------------------------------------------------------
// flash attention + epilogue.
// block: (m_tile=64 queries) x (c_tile=128 channels), 256 threads = 4 waves,
// wave w owns query rows w*16..w*16+15. Lane roles:
//   QK^T phase: lane = key index (64 keys/tile)
//   PV  phase: lane = channel pair (c = 2*lane, 2*lane+1 within tile)
// out[b][c][i] = alpha * (sum_j softmax_j(S[i,:])[j] * v[c][j]) + x[b][c][i]
// ---------------------------------------------------------------------------
__global__ __launch_bounds__(256) void attn_kernel(
    const float* __restrict__ q, const float* __restrict__ k,
    const float* __restrict__ v, const float* __restrict__ x,
    const float* __restrict__ alpha, float* __restrict__ out) {
  const int b   = blockIdx.z;
  const int m0  = blockIdx.x * 64;    // query tile base
  const int ct0 = blockIdx.y * 128;   // channel tile base
  __shared__ float qs[64][68];        // [query][o], b128-readable rows
  __shared__ float ks[64][64];        // [o][key]
  __shared__ float vt[64][130];       // [key][c], +2 pad
  __shared__ float ps[4][64][24];     // [wave][key][m], b128-readable rows
  const int t    = threadIdx.x;
  const int lane = t & 63;
  const int w    = t >> 6;

  // stage Q tile: q[b][o][m0+mm] -> qs[mm][o]
  {
    const float* qb = q + (size_t)b * C8_ * N_ + m0;
#pragma unroll
    for (int i = 0; i < 16; ++i) {
      int idx = t + i * 256;          // 0..4095
      int o = idx >> 6, mm = idx & 63;
      qs[mm][o] = qb[(size_t)o * N_ + mm];
    }
  }

  float acc0[16], acc1[16], rmax[16], rsum[16];
#pragma unroll
  for (int i = 0; i < 16; ++i) {
    acc0[i] = 0.f; acc1[i] = 0.f; rmax[i] = -1e30f; rsum[i] = 0.f;
  }

  const float*  kb  = k + (size_t)b * C8_ * N_;
  const float4* vb4 = (const float4*)(v + ((size_t)b * C_ + ct0) * N_);

  for (int n0 = 0; n0 < N_; n0 += 64) {
    __syncthreads();
    // stage K tile: 64o x 64n as float4 (conflict-free LDS writes)
#pragma unroll
    for (int i = 0; i < 4; ++i) {
      int idx = t + i * 256;          // 0..1023
      int o = idx >> 4, nn4 = idx & 15;
      float4 kk = ((const float4*)(kb + (size_t)o * N_ + n0))[nn4];
      ((float4*)&ks[o][0])[nn4] = kk;
    }
    // stage V tile transposed: v[c][n] -> vt[n][c] (128c x 64n)
#pragma unroll
    for (int i = 0; i < 8; ++i) {
      int idx = t + i * 256;          // 0..2047
      int c = idx >> 4, nn4 = idx & 15;
      float4 vv = vb4[(size_t)c * (N_ / 4) + (n0 >> 2) + nn4];
      vt[nn4 * 4 + 0][c] = vv.x;
      vt[nn4 * 4 + 1][c] = vv.y;
      vt[nn4 * 4 + 2][c] = vv.z;
      vt[nn4 * 4 + 3][c] = vv.w;
    }
    __syncthreads();

    // ---- QK^T: lane = key j, loop 16 query rows of this wave
    float s[16];
#pragma unroll
    for (int m = 0; m < 16; ++m) s[m] = 0.f;
#pragma unroll
    for (int o4 = 0; o4 < 16; ++o4) {
      float k0 = ks[o4 * 4 + 0][lane];
      float k1 = ks[o4 * 4 + 1][lane];
      float k2 = ks[o4 * 4 + 2][lane];
      float k3 = ks[o4 * 4 + 3][lane];
#pragma unroll
      for (int m = 0; m < 16; ++m) {
        float4 q4 = ((const float4*)&qs[w * 16 + m][0])[o4];  // broadcast
        s[m] += q4.x * k0 + q4.y * k1 + q4.z * k2 + q4.w * k3;
      }
    }

    // ---- online softmax per query row (wave-wide over 64 keys)
#pragma unroll
    for (int m = 0; m < 16; ++m) {
      float sm = s[m];
#pragma unroll
      for (int off = 32; off > 0; off >>= 1)
        sm = fmaxf(sm, __shfl_xor(sm, off));
      float mnew = fmaxf(rmax[m], sm);
      float p    = __expf(s[m] - mnew);
      float psum = p;
#pragma unroll
      for (int off = 32; off > 0; off >>= 1)
        psum += __shfl_xor(psum, off);
      float corr = __expf(rmax[m] - mnew);
      rmax[m] = mnew;
      rsum[m] = rsum[m] * corr + psum;
      acc0[m] *= corr;
      acc1[m] *= corr;
      ps[w][lane][m] = p;   // same-wave producer/consumer: no barrier needed
    }

    // ---- PV: lane = channel pair (2*lane, 2*lane+1)
#pragma unroll 4
    for (int n = 0; n < 64; ++n) {
      float2 v2 = ((const float2*)&vt[n][0])[lane];
#pragma unroll
      for (int m4 = 0; m4 < 4; ++m4) {
        float4 p4 = ((const float4*)&ps[w][n][0])[m4];  // broadcast
        acc0[m4 * 4 + 0] += p4.x * v2.x;  acc1[m4 * 4 + 0] += p4.x * v2.y;
        acc0[m4 * 4 + 1] += p4.y * v2.x;  acc1[m4 * 4 + 1] += p4.y * v2.y;
        acc0[m4 * 4 + 2] += p4.z * v2.x;  acc1[m4 * 4 + 2] += p4.z * v2.y;
        acc0[m4 * 4 + 3] += p4.w * v2.x;  acc1[m4 * 4 + 3] += p4.w * v2.y;
      }
    }
  }

  // ---- epilogue: out = alpha * (acc / rsum) + x
  const float a0  = alpha[0];
  const int   c0g = ct0 + 2 * lane, c1g = c0g + 1;
#pragma unroll
  for (int m = 0; m < 16; ++m) {
    int   mg  = m0 + w * 16 + m;
    float inv = 1.0f / rsum[m];
    size_t i0 = ((size_t)b * C_ + c0g) * N_ + mg;
    size_t i1 = ((size_t)b * C_ + c1g) * N_ + mg;
    out[i0] = a0 * (acc0[m] * inv) + x[i0];
    out[i1] = a0 * (acc1[m] * inv) + x[i1];
  }
}

extern "C" void kernel_launch(void* const* d_in, const int* in_sizes, int n_in,
                              void* d_out, int out_size, void* d_ws, size_t ws_size,
                              hipStream_t stream) {
  const float* x     = (const float*)d_in[0];
  const float* w_b   = (const float*)d_in[1];
  const float* b_b   = (const float*)d_in[2];
  const float* w_c   = (const float*)d_in[3];
  const float* b_c   = (const float*)d_in[4];
  const float* w_d   = (const float*)d_in[5];
  const float* b_d   = (const float*)d_in[6];
  const float* alpha = (const float*)d_in[7];
  float* out = (float*)d_out;

  // workspace: Q[8][64][4096] | K[8][64][4096] | V[8][512][4096]  (~84 MB fp32)
  float* Q = (float*)d_ws;
  float* K = Q + (size_t)B_ * C8_ * N_;
  float* V = K + (size_t)B_ * C8_ * N_;

  proj_kernel<<<dim3(N_ / 64, C8_ / 64, B_), 256, 0, stream>>>(x, w_b, b_b, Q, C8_);
  proj_kernel<<<dim3(N_ / 64, C8_ / 64, B_), 256, 0, stream>>>(x, w_c, b_c, K, C8_);
  proj_kernel<<<dim3(N_ / 64, C_ / 64, B_), 256, 0, stream>>>(x, w_d, b_d, V, C_);
  attn_kernel<<<dim3(N_ / 64, C_ / 128, B_), 256, 0, stream>>>(Q, K, V, x, alpha, out);
}

// Round 2
// 676.408 us; speedup vs baseline: 19.9962x; 19.9962x over previous
//
#include <hip/hip_runtime.h>
#include <hip/hip_bf16.h>

#define B_   8
#define C_   512
#define C8_  64
#define N_   4096   // 64*64 spatial

typedef __attribute__((ext_vector_type(8))) short bf16x8;
typedef __attribute__((ext_vector_type(4))) float f32x4;

#define MFMA16(A, Bv, Cv) __builtin_amdgcn_mfma_f32_16x16x32_bf16((A), (Bv), (Cv), 0, 0, 0)

// ---------------------------------------------------------------------------
// proj_t: out[o][n] = sum_c W[o][c] x[c][n] + b[o], O=64.
// Writes bf16 TRANSPOSED: outT[b][n][o]  (so attn MFMA frags are contiguous).
// ---------------------------------------------------------------------------
__global__ __launch_bounds__(256) void proj_t_kernel(
    const float* __restrict__ x, const float* __restrict__ W,
    const float* __restrict__ bias, __hip_bfloat16* __restrict__ outT) {
  const int b  = blockIdx.z;
  const int n0 = blockIdx.x * 64;
  __shared__ float xs[32][64];
  __shared__ float wsT[32][68];
  const int t = threadIdx.x, tn = t & 15, to = t >> 4;

  float acc[4][4];
#pragma unroll
  for (int i = 0; i < 4; ++i)
#pragma unroll
    for (int j = 0; j < 4; ++j) acc[i][j] = 0.f;

  const float* xb = x + (size_t)b * C_ * N_ + n0;
  for (int c0 = 0; c0 < C_; c0 += 32) {
#pragma unroll
    for (int i = 0; i < 8; ++i) {
      int idx = t + i * 256;
      int cc = idx >> 6, nn = idx & 63;
      xs[cc][nn] = xb[(size_t)(c0 + cc) * N_ + nn];
    }
#pragma unroll
    for (int i = 0; i < 8; ++i) {
      int idx = t + i * 256;
      int cc = idx & 31, oo = idx >> 5;
      wsT[cc][oo] = W[(size_t)oo * C_ + c0 + cc];
    }
    __syncthreads();
#pragma unroll
    for (int cc = 0; cc < 32; ++cc) {
      float4 xv = ((const float4*)&xs[cc][0])[tn];
      float4 wv = ((const float4*)&wsT[cc][0])[to];
      acc[0][0] += wv.x * xv.x; acc[0][1] += wv.x * xv.y;
      acc[0][2] += wv.x * xv.z; acc[0][3] += wv.x * xv.w;
      acc[1][0] += wv.y * xv.x; acc[1][1] += wv.y * xv.y;
      acc[1][2] += wv.y * xv.z; acc[1][3] += wv.y * xv.w;
      acc[2][0] += wv.z * xv.x; acc[2][1] += wv.z * xv.y;
      acc[2][2] += wv.z * xv.z; acc[2][3] += wv.z * xv.w;
      acc[3][0] += wv.w * xv.x; acc[3][1] += wv.w * xv.y;
      acc[3][2] += wv.w * xv.z; acc[3][3] += wv.w * xv.w;
    }
    __syncthreads();
  }
  // transposed bf16 write: outT[(b*N + n)*64 + o], 4 o-contig bf16 = 8B chunks
#pragma unroll
  for (int j = 0; j < 4; ++j) {
    int nn = n0 + tn * 4 + j;
    __hip_bfloat16 h[4];
#pragma unroll
    for (int i = 0; i < 4; ++i)
      h[i] = __float2bfloat16(acc[i][j] + bias[to * 4 + i]);
    *(ushort4*)&outT[((size_t)b * N_ + nn) * 64 + to * 4] = *(ushort4*)h;
  }
}

// ---------------------------------------------------------------------------
// proj_v: bf16 output in natural layout out[b][c][n]
// ---------------------------------------------------------------------------
__global__ __launch_bounds__(256) void proj_v_kernel(
    const float* __restrict__ x, const float* __restrict__ W,
    const float* __restrict__ bias, __hip_bfloat16* __restrict__ out) {
  const int b  = blockIdx.z;
  const int n0 = blockIdx.x * 64;
  const int o0 = blockIdx.y * 64;
  __shared__ float xs[32][64];
  __shared__ float wsT[32][68];
  const int t = threadIdx.x, tn = t & 15, to = t >> 4;

  float acc[4][4];
#pragma unroll
  for (int i = 0; i < 4; ++i)
#pragma unroll
    for (int j = 0; j < 4; ++j) acc[i][j] = 0.f;

  const float* xb = x + (size_t)b * C_ * N_ + n0;
  for (int c0 = 0; c0 < C_; c0 += 32) {
#pragma unroll
    for (int i = 0; i < 8; ++i) {
      int idx = t + i * 256;
      int cc = idx >> 6, nn = idx & 63;
      xs[cc][nn] = xb[(size_t)(c0 + cc) * N_ + nn];
    }
#pragma unroll
    for (int i = 0; i < 8; ++i) {
      int idx = t + i * 256;
      int cc = idx & 31, oo = idx >> 5;
      wsT[cc][oo] = W[(size_t)(o0 + oo) * C_ + c0 + cc];
    }
    __syncthreads();
#pragma unroll
    for (int cc = 0; cc < 32; ++cc) {
      float4 xv = ((const float4*)&xs[cc][0])[tn];
      float4 wv = ((const float4*)&wsT[cc][0])[to];
      acc[0][0] += wv.x * xv.x; acc[0][1] += wv.x * xv.y;
      acc[0][2] += wv.x * xv.z; acc[0][3] += wv.x * xv.w;
      acc[1][0] += wv.y * xv.x; acc[1][1] += wv.y * xv.y;
      acc[1][2] += wv.y * xv.z; acc[1][3] += wv.y * xv.w;
      acc[2][0] += wv.z * xv.x; acc[2][1] += wv.z * xv.y;
      acc[2][2] += wv.z * xv.z; acc[2][3] += wv.z * xv.w;
      acc[3][0] += wv.w * xv.x; acc[3][1] += wv.w * xv.y;
      acc[3][2] += wv.w * xv.z; acc[3][3] += wv.w * xv.w;
    }
    __syncthreads();
  }
#pragma unroll
  for (int i = 0; i < 4; ++i) {
    int oo = to * 4 + i;
    float bv = bias[o0 + oo];
    __hip_bfloat16 h[4];
#pragma unroll
    for (int j = 0; j < 4; ++j) h[j] = __float2bfloat16(acc[i][j] + bv);
    *(ushort4*)&out[((size_t)b * C_ + o0 + oo) * N_ + n0 + tn * 4] = *(ushort4*)h;
  }
}

// ---------------------------------------------------------------------------
// MFMA flash attention + epilogue. Block = 64 queries x ALL 512 channels,
// 8 waves (512 thr). Per 64-key tile:
//   QK^T: wave w -> S frag rows 16*(w&3), keys 32*(w>>2)+{0..31}: 4 MFMA,
//         operands direct from global (Qt/Kt are [n][64] bf16, contiguous frags)
//   exp (no max-subtract; clamp 70) -> P bf16 to padded LDS [64][72]
//   PV:   wave w owns channels 64w..64w+63: 32 MFMA, V frags direct from global
// No-rescale online softmax: rsum accumulated lane-locally, reduced at end.
// out = (alpha/rsum) * acc + x
// ---------------------------------------------------------------------------
__global__ __launch_bounds__(512) void attn2_kernel(
    const __hip_bfloat16* __restrict__ Qt,  // [B][N][64]
    const __hip_bfloat16* __restrict__ Kt,  // [B][N][64]
    const __hip_bfloat16* __restrict__ V,   // [B][C][N]
    const float* __restrict__ x,
    const float* __restrict__ alpha,
    float* __restrict__ out) {
  const int b  = blockIdx.y;
  const int m0 = blockIdx.x * 64;
  const int t  = threadIdx.x;
  const int w  = t >> 6, l = t & 63, g = l >> 4, cl = l & 15;
  const int mf = w & 3;    // this wave's S-frag query rows: 16*mf..16*mf+15
  const int jh = w >> 2;   // this wave's key half: 32*jh..32*jh+31

  __shared__ __hip_bfloat16 pt[64 * 72];  // P[m][j], pitch 72 bf16 = 144B
  __shared__ float rs[2][64];

  // resident Q A-frags (row = l&15, k = 8*(l>>4)+i, two k-steps)
  const __hip_bfloat16* qp =
      Qt + ((size_t)b * N_ + m0 + 16 * mf + cl) * 64 + g * 8;
  bf16x8 qa0 = *(const bf16x8*)(qp);
  bf16x8 qa1 = *(const bf16x8*)(qp + 32);

  f32x4 acc[4][4];  // [cf][mfp]
#pragma unroll
  for (int i = 0; i < 4; ++i)
#pragma unroll
    for (int j = 0; j < 4; ++j) acc[i][j] = (f32x4){0.f, 0.f, 0.f, 0.f};
  float prsum[4] = {0.f, 0.f, 0.f, 0.f};

  const __hip_bfloat16* kbase = Kt + (size_t)b * N_ * 64;
  const __hip_bfloat16* vbase = V + (size_t)b * C_ * N_;

  for (int n0 = 0; n0 < N_; n0 += 64) {
    // ---- QK^T: 4 MFMA
    f32x4 s0 = {0.f, 0.f, 0.f, 0.f}, s1 = {0.f, 0.f, 0.f, 0.f};
#pragma unroll
    for (int kk = 0; kk < 2; ++kk) {
      const __hip_bfloat16* kp =
          kbase + ((size_t)(n0 + 32 * jh + cl)) * 64 + kk * 32 + g * 8;
      bf16x8 kb0 = *(const bf16x8*)(kp);            // keys j0..j0+15
      bf16x8 kb1 = *(const bf16x8*)(kp + 16 * 64);  // keys j0+16..j0+31
      bf16x8 qa = kk ? qa1 : qa0;
      s0 = MFMA16(qa, kb0, s0);
      s1 = MFMA16(qa, kb1, s1);
    }

    __syncthreads();  // previous tile's PV done reading pt
    // ---- exp + P write + lane-local rsum
#pragma unroll
    for (int jf = 0; jf < 2; ++jf) {
      f32x4 sv = jf ? s1 : s0;
#pragma unroll
      for (int r = 0; r < 4; ++r) {
        float e = __expf(fminf(sv[r], 70.f));
        prsum[r] += e;
        pt[(16 * mf + 4 * g + r) * 72 + 32 * jh + 16 * jf + cl] =
            __float2bfloat16(e);
      }
    }
    __syncthreads();  // pt ready

    // ---- PV: 32 MFMA, wave owns channels 64w..64w+63
#pragma unroll
    for (int kk = 0; kk < 2; ++kk) {
      bf16x8 pb[4];
#pragma unroll
      for (int mfp = 0; mfp < 4; ++mfp)
        pb[mfp] = *(const bf16x8*)&pt[(16 * mfp + cl) * 72 + kk * 32 + g * 8];
#pragma unroll
      for (int cf = 0; cf < 4; ++cf) {
        bf16x8 va = *(const bf16x8*)&vbase[(size_t)(64 * w + 16 * cf + cl) * N_ +
                                           n0 + kk * 32 + g * 8];
#pragma unroll
        for (int mfp = 0; mfp < 4; ++mfp)
          acc[cf][mfp] = MFMA16(va, pb[mfp], acc[cf][mfp]);
      }
    }
  }

  // ---- rsum: reduce over the 16 key-lanes, combine two key-halves via LDS
#pragma unroll
  for (int r = 0; r < 4; ++r) {
    float v = prsum[r];
    v += __shfl_xor(v, 1);
    v += __shfl_xor(v, 2);
    v += __shfl_xor(v, 4);
    v += __shfl_xor(v, 8);
    if (cl == 0) rs[jh][16 * mf + 4 * g + r] = v;
  }
  __syncthreads();

  // ---- epilogue: out = (alpha/rsum)*acc + x
  const float a0 = alpha[0];
#pragma unroll
  for (int mfp = 0; mfp < 4; ++mfp) {
    int n = m0 + 16 * mfp + cl;
    float inv = a0 / (rs[0][16 * mfp + cl] + rs[1][16 * mfp + cl]);
#pragma unroll
    for (int cf = 0; cf < 4; ++cf) {
      int c = 64 * w + 16 * cf + 4 * g;
#pragma unroll
      for (int r = 0; r < 4; ++r) {
        size_t idx = ((size_t)b * C_ + c + r) * N_ + n;
        out[idx] = acc[cf][mfp][r] * inv + x[idx];
      }
    }
  }
}

extern "C" void kernel_launch(void* const* d_in, const int* in_sizes, int n_in,
                              void* d_out, int out_size, void* d_ws, size_t ws_size,
                              hipStream_t stream) {
  const float* x     = (const float*)d_in[0];
  const float* w_b   = (const float*)d_in[1];
  const float* b_b   = (const float*)d_in[2];
  const float* w_c   = (const float*)d_in[3];
  const float* b_c   = (const float*)d_in[4];
  const float* w_d   = (const float*)d_in[5];
  const float* b_d   = (const float*)d_in[6];
  const float* alpha = (const float*)d_in[7];
  float* out = (float*)d_out;

  // ws: Qt[8][4096][64] bf16 | Kt[8][4096][64] bf16 | V[8][512][4096] bf16 (40MB)
  __hip_bfloat16* Qt = (__hip_bfloat16*)d_ws;
  __hip_bfloat16* Kt = Qt + (size_t)B_ * N_ * C8_;
  __hip_bfloat16* Vb = Kt + (size_t)B_ * N_ * C8_;

  proj_t_kernel<<<dim3(N_ / 64, 1, B_), 256, 0, stream>>>(x, w_b, b_b, Qt);
  proj_t_kernel<<<dim3(N_ / 64, 1, B_), 256, 0, stream>>>(x, w_c, b_c, Kt);
  proj_v_kernel<<<dim3(N_ / 64, C_ / 64, B_), 256, 0, stream>>>(x, w_d, b_d, Vb);
  attn2_kernel<<<dim3(N_ / 64, B_), 512, 0, stream>>>(Qt, Kt, Vb, x, alpha, out);
}

// Round 3
// 660.318 us; speedup vs baseline: 20.4834x; 1.0244x over previous
//
#include <hip/hip_runtime.h>
#include <hip/hip_bf16.h>

#define B_   8
#define C_   512
#define C8_  64
#define N_   4096   // 64*64 spatial

typedef __attribute__((ext_vector_type(8))) short bf16x8;
typedef __attribute__((ext_vector_type(4))) float f32x4;

#define MFMA16(A, Bv, Cv) __builtin_amdgcn_mfma_f32_16x16x32_bf16((A), (Bv), (Cv), 0, 0, 0)

static __device__ __forceinline__ ushort f2bu(float f) {
  __hip_bfloat16 h = __float2bfloat16(f);
  return *reinterpret_cast<ushort*>(&h);
}

// ---------------------------------------------------------------------------
// cast_xt: x[b][c][n] fp32 -> xT[b][n][c] bf16 (LDS 64x64 tile transpose)
// ---------------------------------------------------------------------------
__global__ __launch_bounds__(256) void cast_xt_kernel(
    const float* __restrict__ x, ushort* __restrict__ xT) {
  const int b = blockIdx.z, c0 = blockIdx.y * 64, n0 = blockIdx.x * 64;
  __shared__ ushort lds[64][66];
  const int t = threadIdx.x, q = t & 15, r = t >> 4;
  const float* xb = x + ((size_t)b * C_ + c0) * N_ + n0;
#pragma unroll
  for (int i = 0; i < 4; ++i) {
    int c = r + 16 * i;
    float4 v = *(const float4*)&xb[(size_t)c * N_ + 4 * q];
    lds[c][4 * q + 0] = f2bu(v.x);
    lds[c][4 * q + 1] = f2bu(v.y);
    lds[c][4 * q + 2] = f2bu(v.z);
    lds[c][4 * q + 3] = f2bu(v.w);
  }
  __syncthreads();
#pragma unroll
  for (int i = 0; i < 4; ++i) {
    int n = r + 16 * i;
    ushort4 o;
    o.x = lds[4 * q + 0][n];
    o.y = lds[4 * q + 1][n];
    o.z = lds[4 * q + 2][n];
    o.w = lds[4 * q + 3][n];
    *(ushort4*)&xT[((size_t)b * N_ + n0 + n) * C_ + c0 + 4 * q] = o;
  }
}

// ---------------------------------------------------------------------------
// cast_w: concat {w_b(64x512), w_c(64x512), w_d(512x512)} fp32 -> bf16 wcat
// ---------------------------------------------------------------------------
__global__ __launch_bounds__(256) void cast_w_kernel(
    const float* __restrict__ wb, const float* __restrict__ wc,
    const float* __restrict__ wd, ushort* __restrict__ wcat) {
  size_t idx = ((size_t)blockIdx.x * 256 + threadIdx.x) * 4;  // 327680 elems
  float4 v;
  if (idx < 32768)       v = *(const float4*)&wb[idx];
  else if (idx < 65536)  v = *(const float4*)&wc[idx - 32768];
  else                   v = *(const float4*)&wd[idx - 65536];
  ushort4 o = {f2bu(v.x), f2bu(v.y), f2bu(v.z), f2bu(v.w)};
  *(ushort4*)&wcat[idx] = o;
}

// ---------------------------------------------------------------------------
// proj_all: one MFMA GEMM for Q^T, K^T, V.  grid = 5120 blocks (XCD-swizzled:
// one batch per XCD => xT tile + weights L2-resident), 256 thr = 4 waves.
// Block: 64 out-channels (o-block) x 64 n.  Wave w: o rows 16w..16w+15.
//   ob 0 -> Qt[b][n][64], ob 1 -> Kt[b][n][64], ob 2..9 -> V[b][c][n]
// ---------------------------------------------------------------------------
__global__ __launch_bounds__(256) void proj_all_kernel(
    const ushort* __restrict__ xT, const ushort* __restrict__ wcat,
    const float* __restrict__ b_b, const float* __restrict__ b_c,
    const float* __restrict__ b_d, ushort* __restrict__ Qt,
    ushort* __restrict__ Kt, ushort* __restrict__ V) {
  const int bid = blockIdx.x;                       // 5120 = 8 XCD * 640
  const int swz = (bid & 7) * 640 + (bid >> 3);
  const int b = swz / 640, rr = swz % 640, ob = rr >> 6, nb = rr & 63;
  const int n0 = nb * 64;
  const int t = threadIdx.x, w = t >> 6, l = t & 63, g = l >> 4, cl = l & 15;

  const ushort* Ws = wcat + (size_t)ob * 64 * 512 + (16 * w + cl) * 512 + 8 * g;
  const ushort* xb = xT + ((size_t)b * N_ + n0 + cl) * C_ + 8 * g;

  f32x4 acc[4];
#pragma unroll
  for (int i = 0; i < 4; ++i) acc[i] = (f32x4){0.f, 0.f, 0.f, 0.f};

  for (int c0 = 0; c0 < C_; c0 += 32) {
    bf16x8 af = *(const bf16x8*)(Ws + c0);
#pragma unroll
    for (int nf = 0; nf < 4; ++nf) {
      bf16x8 bfr = *(const bf16x8*)(xb + (size_t)(16 * nf) * C_ + c0);
      acc[nf] = MFMA16(af, bfr, acc[nf]);
    }
  }

  if (ob < 2) {  // transposed bf16 [n][64] + bias
    ushort* dst = (ob == 0 ? Qt : Kt) + (size_t)b * N_ * 64;
    const float* bias = (ob == 0 ? b_b : b_c);
    float b0 = bias[16 * w + 4 * g + 0], b1 = bias[16 * w + 4 * g + 1];
    float b2 = bias[16 * w + 4 * g + 2], b3 = bias[16 * w + 4 * g + 3];
#pragma unroll
    for (int nf = 0; nf < 4; ++nf) {
      int n = n0 + 16 * nf + cl;
      ushort4 o = {f2bu(acc[nf][0] + b0), f2bu(acc[nf][1] + b1),
                   f2bu(acc[nf][2] + b2), f2bu(acc[nf][3] + b3)};
      *(ushort4*)&dst[(size_t)n * 64 + 16 * w + 4 * g] = o;
    }
  } else {  // V natural bf16 [c][n] + bias
    int c0g = (ob - 2) * 64 + 16 * w + 4 * g;
#pragma unroll
    for (int r = 0; r < 4; ++r) {
      float bv = b_d[c0g + r];
      ushort* vrow = V + ((size_t)b * C_ + c0g + r) * N_;
#pragma unroll
      for (int nf = 0; nf < 4; ++nf)
        vrow[n0 + 16 * nf + cl] = f2bu(acc[nf][r] + bv);
    }
  }
}

// ---------------------------------------------------------------------------
// attn3: MFMA flash attention. Block = 64 q x 512 c, 8 waves.
// Per 64-key tile: K loads + V(kk=0) loads issued at top; QK 4 MFMA; exp ->
// pt[p] (dbuf); lgkmcnt-only barrier (global loads stay in flight); V(kk=1)
// loads; PV 32 MFMA with setprio. One barrier per tile.
// ---------------------------------------------------------------------------
__global__ __launch_bounds__(512, 4) void attn3_kernel(
    const ushort* __restrict__ Qt, const ushort* __restrict__ Kt,
    const ushort* __restrict__ V, const float* __restrict__ x,
    const float* __restrict__ alpha, float* __restrict__ out) {
  const int bid = blockIdx.x;                   // 512 = 8 XCD * 64
  const int swz = (bid & 7) * 64 + (bid >> 3);
  const int b = swz >> 6, m0 = (swz & 63) * 64;
  const int t = threadIdx.x;
  const int w = t >> 6, l = t & 63, g = l >> 4, cl = l & 15;
  const int mf = w & 3, jh = w >> 2;

  __shared__ ushort pt[2][64 * 88];   // P[m][j], pitch 88 (176B, 16B-aligned)
  __shared__ float  rs[2][64];

  const ushort* qp = Qt + ((size_t)b * N_ + m0 + 16 * mf + cl) * 64 + g * 8;
  bf16x8 qa0 = *(const bf16x8*)(qp);
  bf16x8 qa1 = *(const bf16x8*)(qp + 32);

  f32x4 acc[4][4];
#pragma unroll
  for (int i = 0; i < 4; ++i)
#pragma unroll
    for (int j = 0; j < 4; ++j) acc[i][j] = (f32x4){0.f, 0.f, 0.f, 0.f};
  float prsum[4] = {0.f, 0.f, 0.f, 0.f};

  const ushort* kbase = Kt + (size_t)b * N_ * 64;
  const ushort* vbase = V + (size_t)b * C_ * N_ + (size_t)(64 * w + cl) * N_;

  for (int n0 = 0; n0 < N_; n0 += 64) {
    const int p = (n0 >> 6) & 1;
    // ---- issue K loads (needed first) and V kk=0 loads (needed after barrier)
    const ushort* kp = kbase + (size_t)(n0 + 32 * jh + cl) * 64 + g * 8;
    bf16x8 k00 = *(const bf16x8*)(kp);
    bf16x8 k01 = *(const bf16x8*)(kp + 16 * 64);
    bf16x8 k10 = *(const bf16x8*)(kp + 32);
    bf16x8 k11 = *(const bf16x8*)(kp + 32 + 16 * 64);
    bf16x8 vv0[4];
#pragma unroll
    for (int cf = 0; cf < 4; ++cf)
      vv0[cf] = *(const bf16x8*)&vbase[(size_t)(16 * cf) * N_ + n0 + g * 8];

    // ---- QK^T
    f32x4 z = {0.f, 0.f, 0.f, 0.f};
    f32x4 s0 = MFMA16(qa0, k00, z);
    f32x4 s1 = MFMA16(qa0, k01, z);
    s0 = MFMA16(qa1, k10, s0);
    s1 = MFMA16(qa1, k11, s1);

    // ---- exp -> pt[p], lane-local rsum
#pragma unroll
    for (int jf = 0; jf < 2; ++jf) {
      f32x4 sv = jf ? s1 : s0;
#pragma unroll
      for (int r = 0; r < 4; ++r) {
        float e = __expf(fminf(sv[r], 70.f));
        prsum[r] += e;
        pt[p][(16 * mf + 4 * g + r) * 88 + 32 * jh + 16 * jf + cl] = f2bu(e);
      }
    }

    // ---- lgkm-only barrier: LDS drained, global loads stay in flight
    asm volatile("s_waitcnt lgkmcnt(0)" ::: "memory");
    __builtin_amdgcn_s_barrier();

    // ---- V kk=1 loads (covered by PV kk=0)
    bf16x8 vv1[4];
#pragma unroll
    for (int cf = 0; cf < 4; ++cf)
      vv1[cf] = *(const bf16x8*)&vbase[(size_t)(16 * cf) * N_ + n0 + 32 + g * 8];

    // ---- PV kk=0
    {
      bf16x8 pb[4];
#pragma unroll
      for (int mfp = 0; mfp < 4; ++mfp)
        pb[mfp] = *(const bf16x8*)&pt[p][(16 * mfp + cl) * 88 + g * 8];
      __builtin_amdgcn_s_setprio(1);
#pragma unroll
      for (int cf = 0; cf < 4; ++cf)
#pragma unroll
        for (int mfp = 0; mfp < 4; ++mfp)
          acc[cf][mfp] = MFMA16(vv0[cf], pb[mfp], acc[cf][mfp]);
      __builtin_amdgcn_s_setprio(0);
    }
    // ---- PV kk=1
    {
      bf16x8 pb[4];
#pragma unroll
      for (int mfp = 0; mfp < 4; ++mfp)
        pb[mfp] = *(const bf16x8*)&pt[p][(16 * mfp + cl) * 88 + 32 + g * 8];
      __builtin_amdgcn_s_setprio(1);
#pragma unroll
      for (int cf = 0; cf < 4; ++cf)
#pragma unroll
        for (int mfp = 0; mfp < 4; ++mfp)
          acc[cf][mfp] = MFMA16(vv1[cf], pb[mfp], acc[cf][mfp]);
      __builtin_amdgcn_s_setprio(0);
    }
  }

  // ---- rsum: reduce over 16 key-lanes, combine halves via LDS
#pragma unroll
  for (int r = 0; r < 4; ++r) {
    float v = prsum[r];
    v += __shfl_xor(v, 1);
    v += __shfl_xor(v, 2);
    v += __shfl_xor(v, 4);
    v += __shfl_xor(v, 8);
    if (cl == 0) rs[jh][16 * mf + 4 * g + r] = v;
  }
  asm volatile("s_waitcnt lgkmcnt(0)" ::: "memory");
  __builtin_amdgcn_s_barrier();

  // ---- epilogue: out = (alpha/rsum)*acc + x
  const float a0 = alpha[0];
#pragma unroll
  for (int mfp = 0; mfp < 4; ++mfp) {
    int n = m0 + 16 * mfp + cl;
    float inv = a0 / (rs[0][16 * mfp + cl] + rs[1][16 * mfp + cl]);
#pragma unroll
    for (int cf = 0; cf < 4; ++cf) {
      int c = 64 * w + 16 * cf + 4 * g;
#pragma unroll
      for (int r = 0; r < 4; ++r) {
        size_t idx = ((size_t)b * C_ + c + r) * N_ + n;
        out[idx] = acc[cf][mfp][r] * inv + x[idx];
      }
    }
  }
}

extern "C" void kernel_launch(void* const* d_in, const int* in_sizes, int n_in,
                              void* d_out, int out_size, void* d_ws, size_t ws_size,
                              hipStream_t stream) {
  const float* x     = (const float*)d_in[0];
  const float* w_b   = (const float*)d_in[1];
  const float* b_b   = (const float*)d_in[2];
  const float* w_c   = (const float*)d_in[3];
  const float* b_c   = (const float*)d_in[4];
  const float* w_d   = (const float*)d_in[5];
  const float* b_d   = (const float*)d_in[6];
  const float* alpha = (const float*)d_in[7];
  float* out = (float*)d_out;

  // ws (bf16/ushort elems): xT 16.78M | Qt 2.1M | Kt 2.1M | V 16.78M | wcat 0.33M
  ushort* xT   = (ushort*)d_ws;
  ushort* Qt   = xT + (size_t)B_ * N_ * C_;
  ushort* Kt   = Qt + (size_t)B_ * N_ * C8_;
  ushort* Vb   = Kt + (size_t)B_ * N_ * C8_;
  ushort* wcat = Vb + (size_t)B_ * C_ * N_;

  cast_xt_kernel<<<dim3(N_ / 64, C_ / 64, B_), 256, 0, stream>>>(x, xT);
  cast_w_kernel<<<320, 256, 0, stream>>>(w_b, w_c, w_d, wcat);
  proj_all_kernel<<<5120, 256, 0, stream>>>(xT, wcat, b_b, b_c, b_d, Qt, Kt, Vb);
  attn3_kernel<<<512, 512, 0, stream>>>(Qt, Kt, Vb, x, alpha, out);
}